// Round 13
// baseline (183.075 us; speedup 1.0000x reference)
//
#include <hip/hip_runtime.h>
#include <hip/hip_bf16.h>

#define LN_EPS 1e-5f
#define BSH   7                  // bucket shift: 128 nodes/bucket
#define BNODE 128
#define EPB   8192               // edges per bucket_scatter block
#define CAP   4096               // max edges per bucket stageable in LDS

// ---------------- CSR prefix build (deg + rowstart) ----------------

__global__ __launch_bounds__(256) void hist_kernel(
    const int* __restrict__ ei, int* __restrict__ deg, int E)
{
    int e = blockIdx.x * 256 + threadIdx.x;
    if (e < E) atomicAdd(&deg[ei[E + e]], 1);
}

__global__ __launch_bounds__(256) void scan1_kernel(
    const int* __restrict__ deg, int* __restrict__ rowstart,
    int* __restrict__ tilesum, int n)
{
    __shared__ int wsum[4];
    int t = threadIdx.x;
    int base = blockIdx.x * 2048 + t * 8;
    int v[8]; int tsum = 0;
    #pragma unroll
    for (int i = 0; i < 8; ++i) { v[i] = (base + i < n) ? deg[base + i] : 0; tsum += v[i]; }
    int lane = t & 63, w = t >> 6;
    int sc = tsum;
    #pragma unroll
    for (int off = 1; off < 64; off <<= 1) {
        int y = __shfl_up(sc, off);
        if (lane >= off) sc += y;
    }
    if (lane == 63) wsum[w] = sc;
    __syncthreads();
    int woff = 0;
    for (int j = 0; j < w; ++j) woff += wsum[j];
    int run = woff + sc - tsum;
    #pragma unroll
    for (int i = 0; i < 8; ++i) { if (base + i < n) rowstart[base + i] = run; run += v[i]; }
    if (t == 255) tilesum[blockIdx.x] = wsum[0] + wsum[1] + wsum[2] + wsum[3];
}

__global__ void scan2_kernel(int* tilesum, int T)
{
    if (blockIdx.x == 0 && threadIdx.x == 0) {
        int run = 0;
        for (int i = 0; i < T; ++i) { int v = tilesum[i]; tilesum[i] = run; run += v; }
    }
}

// also seeds gcursor[b] = rowstart[b*128]
__global__ __launch_bounds__(256) void scan3_kernel(
    int* __restrict__ rowstart, const int* __restrict__ tilesum,
    int* __restrict__ gcursor, int n, int E)
{
    int i = blockIdx.x * 256 + threadIdx.x;
    if (i < n) {
        int v = rowstart[i] + tilesum[i >> 11];
        rowstart[i] = v;
        if ((i & (BNODE - 1)) == 0) gcursor[i >> BSH] = v;
    }
    if (i == 0) rowstart[n] = E;
}

// ---------------- bucket scatter ----------------
__global__ __launch_bounds__(256) void bucket_scatter_kernel(
    const int* __restrict__ ei,
    int* __restrict__ gcursor,
    int* __restrict__ ebuf,
    int E, int NB)
{
    __shared__ int lhist[1024];   // NB = 782 for N = 100k
    __shared__ int lbase[1024];
    __shared__ int lcur[1024];

    int t = threadIdx.x;
    int base = blockIdx.x * EPB;

    for (int b = t; b < NB; b += 256) lhist[b] = 0;
    __syncthreads();

    #pragma unroll 4
    for (int i = 0; i < EPB / 256; ++i) {
        int e = base + i * 256 + t;          // coalesced
        if (e < E) atomicAdd(&lhist[ei[E + e] >> BSH], 1);
    }
    __syncthreads();

    for (int b = t; b < NB; b += 256) {
        int c = lhist[b];
        lbase[b] = c ? atomicAdd(&gcursor[b], c) : 0;
        lcur[b]  = 0;
    }
    __syncthreads();

    #pragma unroll 4
    for (int i = 0; i < EPB / 256; ++i) {
        int e = base + i * 256 + t;
        if (e < E) {
            int src = ei[e];
            int dst = ei[E + e];
            int b   = dst >> BSH;
            int pos = lbase[b] + atomicAdd(&lcur[b], 1);
            ebuf[pos] = src | ((dst & (BNODE - 1)) << 17);
        }
    }
}

// ---------------- csrsort: bucket -> exact CSR order via LDS ----------------
__global__ __launch_bounds__(256) void csrsort_kernel(
    const int* __restrict__ rowstart,
    const int* __restrict__ ebuf,
    int* __restrict__ esrc,
    int N)
{
    __shared__ int rbase[BNODE + 1];
    __shared__ int lcur[BNODE];
    __shared__ int sorted[CAP];

    int t    = threadIdx.x;
    int nb0  = blockIdx.x << BSH;
    int top  = min(nb0 + BNODE, N);
    int nloc = top - nb0;

    for (int i = t; i <= nloc; i += 256) rbase[i] = rowstart[nb0 + i];
    for (int i = t; i < nloc;  i += 256) lcur[i] = 0;
    __syncthreads();

    int s0 = rbase[0], s1 = rbase[nloc];
    int cnt = s1 - s0;

    if (cnt <= CAP) {
        for (int i = s0 + t; i < s1; i += 256) {
            int p = ebuf[i];
            int n = p >> 17;
            int slot = (rbase[n] - s0) + atomicAdd(&lcur[n], 1);
            sorted[slot] = p & 0x1FFFF;
        }
        __syncthreads();
        for (int i = t; i < cnt; i += 256) esrc[s0 + i] = sorted[i];  // coalesced
    } else {
        for (int i = s0 + t; i < s1; i += 256) {
            int p = ebuf[i];
            int n = p >> 17;
            int slot = rbase[n] + atomicAdd(&lcur[n], 1);
            esrc[slot] = p & 0x1FFFF;
        }
    }
}

// ---------------- gather: CSR mean-aggregate (round-3 proven) ----------------
__global__ __launch_bounds__(256) void gather_kernel(
    const float* __restrict__ x,
    const int*   __restrict__ rowstart,
    const int*   __restrict__ esrc,
    float* __restrict__ mean,
    int N)
{
    int tid  = threadIdx.x;
    int lane = tid & 63;
    int g    = lane >> 4;
    int l4   = (lane & 15) * 4;
    int node = blockIdx.x * 4 + (tid >> 6);
    if (node >= N) return;
    int s0 = rowstart[node], s1 = rowstart[node + 1];

    float4 a0 = make_float4(0.f, 0.f, 0.f, 0.f);
    float4 a1 = make_float4(0.f, 0.f, 0.f, 0.f);
    int e = s0 + g;
    for (; e + 4 < s1; e += 8) {
        int sA = esrc[e];
        int sB = esrc[e + 4];
        float4 va = *(const float4*)&x[(size_t)sA * 64 + l4];
        float4 vb = *(const float4*)&x[(size_t)sB * 64 + l4];
        a0.x += va.x; a0.y += va.y; a0.z += va.z; a0.w += va.w;
        a1.x += vb.x; a1.y += vb.y; a1.z += vb.z; a1.w += vb.w;
    }
    if (e < s1) {
        float4 va = *(const float4*)&x[(size_t)esrc[e] * 64 + l4];
        a0.x += va.x; a0.y += va.y; a0.z += va.z; a0.w += va.w;
    }
    a0.x += a1.x; a0.y += a1.y; a0.z += a1.z; a0.w += a1.w;

    a0.x += __shfl_xor(a0.x, 32); a0.y += __shfl_xor(a0.y, 32);
    a0.z += __shfl_xor(a0.z, 32); a0.w += __shfl_xor(a0.w, 32);
    a0.x += __shfl_xor(a0.x, 16); a0.y += __shfl_xor(a0.y, 16);
    a0.z += __shfl_xor(a0.z, 16); a0.w += __shfl_xor(a0.w, 16);

    if (g == 0) {
        float inv = 1.0f / fmaxf((float)(s1 - s0), 1.0f);
        float4 r = make_float4(a0.x * inv, a0.y * inv, a0.z * inv, a0.w * inv);
        *(float4*)&mean[(size_t)node * 64 + l4] = r;
    }
}

// ---------------- MLP + LayerNorm + ELU ----------------
// Round-10 structure (thread=node, wave=j-quarter, s_load weights via
// readfirstlane'd part), with the INPUT PATH fixed: lane=node means direct
// per-lane row reads are stride-256B -> each float4 load instruction touches
// 64 distinct cache lines (fully uncoalesced; ~12.8M line-transactions total
// = ~21us of TA-pipe serialization = the round-10/12 floor). Fix: cooperative
// COALESCED staging of the block's 64 mean/x rows into padded LDS ([64][65],
// bank (lane+col)%32 -> 2-way = free), then ds_read_b32 in the fmac loop.
// c-loop stays rolled (round-11: unrolling blows the SGPR weight window).
__global__ __launch_bounds__(256, 4) void mlp_kernel(
    const float* __restrict__ x,
    const float* mean,              // aliases out - no restrict
    const float* __restrict__ Wl,
    const float* __restrict__ Wr,
    const float* __restrict__ bias,
    const float* __restrict__ gamma,
    const float* __restrict__ beta,
    float* out,
    int N)
{
    __shared__ float smean[64][65];
    __shared__ float sx[64][65];
    __shared__ float sp[4][64];
    __shared__ float sq[4][64];

    int tid  = threadIdx.x;
    int lane = tid & 63;
    int part = __builtin_amdgcn_readfirstlane(tid >> 6); // SGPR-pinned
    int nbase = blockIdx.x * 64;
    int node  = nbase + lane;
    bool act  = node < N;

    // Phase 1: coalesced cooperative stage (each f4 slot = 16B contiguous;
    // consecutive threads -> consecutive addresses -> 4 lines per instr).
    #pragma unroll
    for (int k = 0; k < 4; ++k) {
        int f4  = tid + k * 256;       // 0..1023 float4 slots
        int row = f4 >> 4;
        int c4  = (f4 & 15) * 4;
        int g   = nbase + row;
        float4 mv, xv;
        if (g < N) {
            mv = *(const float4*)&mean[(size_t)g * 64 + c4];
            xv = *(const float4*)&x[(size_t)g * 64 + c4];
        } else {
            mv = make_float4(0.f, 0.f, 0.f, 0.f);
            xv = make_float4(0.f, 0.f, 0.f, 0.f);
        }
        smean[row][c4 + 0] = mv.x; smean[row][c4 + 1] = mv.y;
        smean[row][c4 + 2] = mv.z; smean[row][c4 + 3] = mv.w;
        sx[row][c4 + 0] = xv.x; sx[row][c4 + 1] = xv.y;
        sx[row][c4 + 2] = xv.z; sx[row][c4 + 3] = xv.w;
    }
    __syncthreads();   // also legalizes mean-aliases-out (all reads precede)

    const float* Wlp = Wl + part * 16 * 64;   // provably uniform -> s_load
    const float* Wrp = Wr + part * 16 * 64;

    float acc[16];
    #pragma unroll
    for (int j = 0; j < 16; ++j) acc[j] = bias[part * 16 + j];

    #pragma unroll 1
    for (int c = 0; c < 8; ++c) {
        float vm[8], vx[8];
        #pragma unroll
        for (int d = 0; d < 8; ++d) {
            vm[d] = smean[lane][c * 8 + d];   // bank (lane+col)%32 -> 2-way free
            vx[d] = sx[lane][c * 8 + d];
        }
        const float* wlc = Wlp + c * 8;       // uniform base -> s_load
        const float* wrc = Wrp + c * 8;
        #pragma unroll
        for (int j = 0; j < 16; ++j) {
            #pragma unroll
            for (int d = 0; d < 8; ++d) {
                acc[j] += wlc[j * 64 + d] * vm[d]
                        + wrc[j * 64 + d] * vx[d];
            }
        }
    }

    float s0 = 0.f, s1 = 0.f, q0 = 0.f, q1 = 0.f;
    #pragma unroll
    for (int j = 0; j < 8; ++j) {
        s0 += acc[j];     q0 += acc[j] * acc[j];
        s1 += acc[j + 8]; q1 += acc[j + 8] * acc[j + 8];
    }
    sp[part][lane] = s0 + s1;
    sq[part][lane] = q0 + q1;
    __syncthreads();

    float st = (sp[0][lane] + sp[1][lane]) + (sp[2][lane] + sp[3][lane]);
    float qt = (sq[0][lane] + sq[1][lane]) + (sq[2][lane] + sq[3][lane]);
    float mu  = st * (1.0f / 64.0f);
    float var = qt * (1.0f / 64.0f) - mu * mu;
    float r   = rsqrtf(var + LN_EPS);

    if (act) {
        #pragma unroll
        for (int cc = 0; cc < 4; ++cc) {
            float4 g4 = *(const float4*)&gamma[part * 16 + cc * 4];
            float4 b4 = *(const float4*)&beta[part * 16 + cc * 4];
            float4 o;
            o.x = (acc[cc*4+0] - mu) * r * g4.x + b4.x;
            o.y = (acc[cc*4+1] - mu) * r * g4.y + b4.y;
            o.z = (acc[cc*4+2] - mu) * r * g4.z + b4.z;
            o.w = (acc[cc*4+3] - mu) * r * g4.w + b4.w;
            o.x = o.x > 0.f ? o.x : __expf(o.x) - 1.0f;
            o.y = o.y > 0.f ? o.y : __expf(o.y) - 1.0f;
            o.z = o.z > 0.f ? o.z : __expf(o.z) - 1.0f;
            o.w = o.w > 0.f ? o.w : __expf(o.w) - 1.0f;
            *(float4*)&out[(size_t)node * 64 + part * 16 + cc * 4] = o;
        }
    }
}

extern "C" void kernel_launch(void* const* d_in, const int* in_sizes, int n_in,
                              void* d_out, int out_size, void* d_ws, size_t ws_size,
                              hipStream_t stream) {
    const float* x     = (const float*)d_in[0];
    const int*   ei    = (const int*)  d_in[1];
    const float* Wl    = (const float*)d_in[2];
    const float* Wr    = (const float*)d_in[3];
    const float* bias  = (const float*)d_in[4];
    const float* gamma = (const float*)d_in[5];
    const float* beta  = (const float*)d_in[6];

    int N  = in_sizes[0] / 64;
    int E  = in_sizes[1] / 2;
    int NB = (N + BNODE - 1) >> BSH;       // 782 buckets

    int* deg      = (int*)d_ws;            // N
    int* rowstart = deg + N;               // N+1
    int* tilesum  = rowstart + (N + 1);    // <=64
    int* gcursor  = tilesum + 64;          // NB
    int* ebuf     = gcursor + NB;          // E (packed src | dstlocal<<17)
    int* esrc     = ebuf + E;              // E (CSR-ordered src)
    float* mean   = (float*)d_out;         // N*64; mlp reads its rows pre-barrier

    hipMemsetAsync(deg, 0, (size_t)N * sizeof(int), stream);

    hist_kernel<<<(E + 255) / 256, 256, 0, stream>>>(ei, deg, E);

    int T = (N + 2047) / 2048;
    scan1_kernel<<<T, 256, 0, stream>>>(deg, rowstart, tilesum, N);
    scan2_kernel<<<1, 64, 0, stream>>>(tilesum, T);
    scan3_kernel<<<(N + 255) / 256, 256, 0, stream>>>(rowstart, tilesum, gcursor, N, E);

    bucket_scatter_kernel<<<(E + EPB - 1) / EPB, 256, 0, stream>>>(ei, gcursor,
                                                                   ebuf, E, NB);

    csrsort_kernel<<<NB, 256, 0, stream>>>(rowstart, ebuf, esrc, N);

    gather_kernel<<<(N + 3) / 4, 256, 0, stream>>>(x, rowstart, esrc, mean, N);

    mlp_kernel<<<(N + 63) / 64, 256, 0, stream>>>(x, mean, Wl, Wr, bias, gamma, beta,
                                                  (float*)d_out, N);
}

// Round 14
// 181.732 us; speedup vs baseline: 1.0074x; 1.0074x over previous
//
#include <hip/hip_runtime.h>
#include <hip/hip_bf16.h>

#define LN_EPS 1e-5f
#define BSH   7                  // bucket shift: 128 nodes/bucket
#define BNODE 128
#define EPB   8192               // edges per bucket_scatter block
#define CAP   4096               // max edges per bucket stageable in LDS

// ---------------- CSR prefix build (deg + rowstart) ----------------

__global__ __launch_bounds__(256) void hist_kernel(
    const int* __restrict__ ei, int* __restrict__ deg, int E)
{
    int e = blockIdx.x * 256 + threadIdx.x;
    if (e < E) atomicAdd(&deg[ei[E + e]], 1);
}

__global__ __launch_bounds__(256) void scan1_kernel(
    const int* __restrict__ deg, int* __restrict__ rowstart,
    int* __restrict__ tilesum, int n)
{
    __shared__ int wsum[4];
    int t = threadIdx.x;
    int base = blockIdx.x * 2048 + t * 8;
    int v[8]; int tsum = 0;
    #pragma unroll
    for (int i = 0; i < 8; ++i) { v[i] = (base + i < n) ? deg[base + i] : 0; tsum += v[i]; }
    int lane = t & 63, w = t >> 6;
    int sc = tsum;
    #pragma unroll
    for (int off = 1; off < 64; off <<= 1) {
        int y = __shfl_up(sc, off);
        if (lane >= off) sc += y;
    }
    if (lane == 63) wsum[w] = sc;
    __syncthreads();
    int woff = 0;
    for (int j = 0; j < w; ++j) woff += wsum[j];
    int run = woff + sc - tsum;
    #pragma unroll
    for (int i = 0; i < 8; ++i) { if (base + i < n) rowstart[base + i] = run; run += v[i]; }
    if (t == 255) tilesum[blockIdx.x] = wsum[0] + wsum[1] + wsum[2] + wsum[3];
}

__global__ void scan2_kernel(int* tilesum, int T)
{
    if (blockIdx.x == 0 && threadIdx.x == 0) {
        int run = 0;
        for (int i = 0; i < T; ++i) { int v = tilesum[i]; tilesum[i] = run; run += v; }
    }
}

// also seeds gcursor[b] = rowstart[b*128]
__global__ __launch_bounds__(256) void scan3_kernel(
    int* __restrict__ rowstart, const int* __restrict__ tilesum,
    int* __restrict__ gcursor, int n, int E)
{
    int i = blockIdx.x * 256 + threadIdx.x;
    if (i < n) {
        int v = rowstart[i] + tilesum[i >> 11];
        rowstart[i] = v;
        if ((i & (BNODE - 1)) == 0) gcursor[i >> BSH] = v;
    }
    if (i == 0) rowstart[n] = E;
}

// ---------------- bucket scatter ----------------
__global__ __launch_bounds__(256) void bucket_scatter_kernel(
    const int* __restrict__ ei,
    int* __restrict__ gcursor,
    int* __restrict__ ebuf,
    int E, int NB)
{
    __shared__ int lhist[1024];   // NB = 782 for N = 100k
    __shared__ int lbase[1024];
    __shared__ int lcur[1024];

    int t = threadIdx.x;
    int base = blockIdx.x * EPB;

    for (int b = t; b < NB; b += 256) lhist[b] = 0;
    __syncthreads();

    #pragma unroll 4
    for (int i = 0; i < EPB / 256; ++i) {
        int e = base + i * 256 + t;          // coalesced
        if (e < E) atomicAdd(&lhist[ei[E + e] >> BSH], 1);
    }
    __syncthreads();

    for (int b = t; b < NB; b += 256) {
        int c = lhist[b];
        lbase[b] = c ? atomicAdd(&gcursor[b], c) : 0;
        lcur[b]  = 0;
    }
    __syncthreads();

    #pragma unroll 4
    for (int i = 0; i < EPB / 256; ++i) {
        int e = base + i * 256 + t;
        if (e < E) {
            int src = ei[e];
            int dst = ei[E + e];
            int b   = dst >> BSH;
            int pos = lbase[b] + atomicAdd(&lcur[b], 1);
            ebuf[pos] = src | ((dst & (BNODE - 1)) << 17);
        }
    }
}

// ---------------- csrsort: bucket -> exact CSR order via LDS ----------------
__global__ __launch_bounds__(256) void csrsort_kernel(
    const int* __restrict__ rowstart,
    const int* __restrict__ ebuf,
    int* __restrict__ esrc,
    int N)
{
    __shared__ int rbase[BNODE + 1];
    __shared__ int lcur[BNODE];
    __shared__ int sorted[CAP];

    int t    = threadIdx.x;
    int nb0  = blockIdx.x << BSH;
    int top  = min(nb0 + BNODE, N);
    int nloc = top - nb0;

    for (int i = t; i <= nloc; i += 256) rbase[i] = rowstart[nb0 + i];
    for (int i = t; i < nloc;  i += 256) lcur[i] = 0;
    __syncthreads();

    int s0 = rbase[0], s1 = rbase[nloc];
    int cnt = s1 - s0;

    if (cnt <= CAP) {
        for (int i = s0 + t; i < s1; i += 256) {
            int p = ebuf[i];
            int n = p >> 17;
            int slot = (rbase[n] - s0) + atomicAdd(&lcur[n], 1);
            sorted[slot] = p & 0x1FFFF;
        }
        __syncthreads();
        for (int i = t; i < cnt; i += 256) esrc[s0 + i] = sorted[i];  // coalesced
    } else {
        for (int i = s0 + t; i < s1; i += 256) {
            int p = ebuf[i];
            int n = p >> 17;
            int slot = rbase[n] + atomicAdd(&lcur[n], 1);
            esrc[slot] = p & 0x1FFFF;
        }
    }
}

// ---------------- gather: CSR mean-aggregate (round-3 proven) ----------------
__global__ __launch_bounds__(256) void gather_kernel(
    const float* __restrict__ x,
    const int*   __restrict__ rowstart,
    const int*   __restrict__ esrc,
    float* __restrict__ mean,
    int N)
{
    int tid  = threadIdx.x;
    int lane = tid & 63;
    int g    = lane >> 4;
    int l4   = (lane & 15) * 4;
    int node = blockIdx.x * 4 + (tid >> 6);
    if (node >= N) return;
    int s0 = rowstart[node], s1 = rowstart[node + 1];

    float4 a0 = make_float4(0.f, 0.f, 0.f, 0.f);
    float4 a1 = make_float4(0.f, 0.f, 0.f, 0.f);
    int e = s0 + g;
    for (; e + 4 < s1; e += 8) {
        int sA = esrc[e];
        int sB = esrc[e + 4];
        float4 va = *(const float4*)&x[(size_t)sA * 64 + l4];
        float4 vb = *(const float4*)&x[(size_t)sB * 64 + l4];
        a0.x += va.x; a0.y += va.y; a0.z += va.z; a0.w += va.w;
        a1.x += vb.x; a1.y += vb.y; a1.z += vb.z; a1.w += vb.w;
    }
    if (e < s1) {
        float4 va = *(const float4*)&x[(size_t)esrc[e] * 64 + l4];
        a0.x += va.x; a0.y += va.y; a0.z += va.z; a0.w += va.w;
    }
    a0.x += a1.x; a0.y += a1.y; a0.z += a1.z; a0.w += a1.w;

    a0.x += __shfl_xor(a0.x, 32); a0.y += __shfl_xor(a0.y, 32);
    a0.z += __shfl_xor(a0.z, 32); a0.w += __shfl_xor(a0.w, 32);
    a0.x += __shfl_xor(a0.x, 16); a0.y += __shfl_xor(a0.y, 16);
    a0.z += __shfl_xor(a0.z, 16); a0.w += __shfl_xor(a0.w, 16);

    if (g == 0) {
        float inv = 1.0f / fmaxf((float)(s1 - s0), 1.0f);
        float4 r = make_float4(a0.x * inv, a0.y * inv, a0.z * inv, a0.w * inv);
        *(float4*)&mean[(size_t)node * 64 + l4] = r;
    }
}

// ---------------- MLP + LayerNorm + ELU ----------------
// Round-12 structure (thread=node, wave=j-quarter, rolled c-loop, s_load
// weights via readfirstlane'd part) with TWO NODES PER THREAD (nbase+lane,
// nbase+64+lane; block covers 128 nodes, grid halves). Rationale: the stuck
// ~47us is the per-chunk scalar-path stall — s_load 2KB + lgkmcnt(0) (SMEM
// returns out-of-order -> all-or-nothing wait), with all waves cycling a
// 32KB weight set through K$. Doubling fmacs per chunk (1024 cyc vs 512)
// halves the stall per FLOP and halves total K$ traffic. r12 no-op and r13
// regression ruled out VMEM-side fixes. LN barrier still separates all mean
// reads (c-loop) from out writes (epilogue) -> aliasing stays legal.
__global__ __launch_bounds__(256, 4) void mlp_kernel(
    const float* __restrict__ x,
    const float* mean,              // aliases out - no restrict
    const float* __restrict__ Wl,
    const float* __restrict__ Wr,
    const float* __restrict__ bias,
    const float* __restrict__ gamma,
    const float* __restrict__ beta,
    float* out,
    int N)
{
    __shared__ float sp[4][128];
    __shared__ float sq[4][128];

    int lane = threadIdx.x & 63;
    int part = __builtin_amdgcn_readfirstlane(threadIdx.x >> 6); // SGPR-pinned
    int nbase = blockIdx.x * 128;
    int n0 = nbase + lane;
    int n1 = nbase + 64 + lane;
    bool v0 = n0 < N, v1 = n1 < N;
    size_t r0 = (size_t)(v0 ? n0 : 0) * 64;
    size_t r1 = (size_t)(v1 ? n1 : 0) * 64;

    const float* Wlp = Wl + part * 16 * 64;   // provably uniform -> s_load
    const float* Wrp = Wr + part * 16 * 64;

    float acc0[16], acc1[16];
    #pragma unroll
    for (int j = 0; j < 16; ++j) {
        float b = bias[part * 16 + j];
        acc0[j] = b; acc1[j] = b;
    }

    #pragma unroll 1
    for (int c = 0; c < 8; ++c) {
        float4 ma0 = *(const float4*)&mean[r0 + c * 8];
        float4 mb0 = *(const float4*)&mean[r0 + c * 8 + 4];
        float4 xa0 = *(const float4*)&x[r0 + c * 8];
        float4 xb0 = *(const float4*)&x[r0 + c * 8 + 4];
        float4 ma1 = *(const float4*)&mean[r1 + c * 8];
        float4 mb1 = *(const float4*)&mean[r1 + c * 8 + 4];
        float4 xa1 = *(const float4*)&x[r1 + c * 8];
        float4 xb1 = *(const float4*)&x[r1 + c * 8 + 4];
        float vm0[8] = {ma0.x, ma0.y, ma0.z, ma0.w, mb0.x, mb0.y, mb0.z, mb0.w};
        float vx0[8] = {xa0.x, xa0.y, xa0.z, xa0.w, xb0.x, xb0.y, xb0.z, xb0.w};
        float vm1[8] = {ma1.x, ma1.y, ma1.z, ma1.w, mb1.x, mb1.y, mb1.z, mb1.w};
        float vx1[8] = {xa1.x, xa1.y, xa1.z, xa1.w, xb1.x, xb1.y, xb1.z, xb1.w};
        const float* wlc = Wlp + c * 8;       // uniform base -> s_load
        const float* wrc = Wrp + c * 8;
        #pragma unroll
        for (int j = 0; j < 16; ++j) {
            #pragma unroll
            for (int d = 0; d < 8; ++d) {
                float wl = wlc[j * 64 + d];
                float wr = wrc[j * 64 + d];
                acc0[j] += wl * vm0[d] + wr * vx0[d];
                acc1[j] += wl * vm1[d] + wr * vx1[d];
            }
        }
    }

    // partial LN stats for both nodes
    {
        float s0 = 0.f, q0 = 0.f, s1 = 0.f, q1 = 0.f;
        #pragma unroll
        for (int j = 0; j < 16; ++j) {
            s0 += acc0[j]; q0 += acc0[j] * acc0[j];
            s1 += acc1[j]; q1 += acc1[j] * acc1[j];
        }
        sp[part][lane]      = s0;  sq[part][lane]      = q0;
        sp[part][64 + lane] = s1;  sq[part][64 + lane] = q1;
    }
    __syncthreads();   // separates ALL mean reads from out writes (aliasing)

    float st0 = (sp[0][lane] + sp[1][lane]) + (sp[2][lane] + sp[3][lane]);
    float qt0 = (sq[0][lane] + sq[1][lane]) + (sq[2][lane] + sq[3][lane]);
    float st1 = (sp[0][64+lane] + sp[1][64+lane]) + (sp[2][64+lane] + sp[3][64+lane]);
    float qt1 = (sq[0][64+lane] + sq[1][64+lane]) + (sq[2][64+lane] + sq[3][64+lane]);
    float mu0  = st0 * (1.0f / 64.0f);
    float var0 = qt0 * (1.0f / 64.0f) - mu0 * mu0;
    float rr0  = rsqrtf(var0 + LN_EPS);
    float mu1  = st1 * (1.0f / 64.0f);
    float var1 = qt1 * (1.0f / 64.0f) - mu1 * mu1;
    float rr1  = rsqrtf(var1 + LN_EPS);

    #pragma unroll
    for (int cc = 0; cc < 4; ++cc) {
        float4 g4 = *(const float4*)&gamma[part * 16 + cc * 4];  // uniform
        float4 b4 = *(const float4*)&beta[part * 16 + cc * 4];
        if (v0) {
            float4 o;
            o.x = (acc0[cc*4+0] - mu0) * rr0 * g4.x + b4.x;
            o.y = (acc0[cc*4+1] - mu0) * rr0 * g4.y + b4.y;
            o.z = (acc0[cc*4+2] - mu0) * rr0 * g4.z + b4.z;
            o.w = (acc0[cc*4+3] - mu0) * rr0 * g4.w + b4.w;
            o.x = o.x > 0.f ? o.x : __expf(o.x) - 1.0f;
            o.y = o.y > 0.f ? o.y : __expf(o.y) - 1.0f;
            o.z = o.z > 0.f ? o.z : __expf(o.z) - 1.0f;
            o.w = o.w > 0.f ? o.w : __expf(o.w) - 1.0f;
            *(float4*)&out[(size_t)n0 * 64 + part * 16 + cc * 4] = o;
        }
        if (v1) {
            float4 o;
            o.x = (acc1[cc*4+0] - mu1) * rr1 * g4.x + b4.x;
            o.y = (acc1[cc*4+1] - mu1) * rr1 * g4.y + b4.y;
            o.z = (acc1[cc*4+2] - mu1) * rr1 * g4.z + b4.z;
            o.w = (acc1[cc*4+3] - mu1) * rr1 * g4.w + b4.w;
            o.x = o.x > 0.f ? o.x : __expf(o.x) - 1.0f;
            o.y = o.y > 0.f ? o.y : __expf(o.y) - 1.0f;
            o.z = o.z > 0.f ? o.z : __expf(o.z) - 1.0f;
            o.w = o.w > 0.f ? o.w : __expf(o.w) - 1.0f;
            *(float4*)&out[(size_t)n1 * 64 + part * 16 + cc * 4] = o;
        }
    }
}

extern "C" void kernel_launch(void* const* d_in, const int* in_sizes, int n_in,
                              void* d_out, int out_size, void* d_ws, size_t ws_size,
                              hipStream_t stream) {
    const float* x     = (const float*)d_in[0];
    const int*   ei    = (const int*)  d_in[1];
    const float* Wl    = (const float*)d_in[2];
    const float* Wr    = (const float*)d_in[3];
    const float* bias  = (const float*)d_in[4];
    const float* gamma = (const float*)d_in[5];
    const float* beta  = (const float*)d_in[6];

    int N  = in_sizes[0] / 64;
    int E  = in_sizes[1] / 2;
    int NB = (N + BNODE - 1) >> BSH;       // 782 buckets

    int* deg      = (int*)d_ws;            // N
    int* rowstart = deg + N;               // N+1
    int* tilesum  = rowstart + (N + 1);    // <=64
    int* gcursor  = tilesum + 64;          // NB
    int* ebuf     = gcursor + NB;          // E (packed src | dstlocal<<17)
    int* esrc     = ebuf + E;              // E (CSR-ordered src)
    float* mean   = (float*)d_out;         // N*64; mlp reads its rows pre-barrier

    hipMemsetAsync(deg, 0, (size_t)N * sizeof(int), stream);

    hist_kernel<<<(E + 255) / 256, 256, 0, stream>>>(ei, deg, E);

    int T = (N + 2047) / 2048;
    scan1_kernel<<<T, 256, 0, stream>>>(deg, rowstart, tilesum, N);
    scan2_kernel<<<1, 64, 0, stream>>>(tilesum, T);
    scan3_kernel<<<(N + 255) / 256, 256, 0, stream>>>(rowstart, tilesum, gcursor, N, E);

    bucket_scatter_kernel<<<(E + EPB - 1) / EPB, 256, 0, stream>>>(ei, gcursor,
                                                                   ebuf, E, NB);

    csrsort_kernel<<<NB, 256, 0, stream>>>(rowstart, ebuf, esrc, N);

    gather_kernel<<<(N + 3) / 4, 256, 0, stream>>>(x, rowstart, esrc, mean, N);

    mlp_kernel<<<(N + 127) / 128, 256, 0, stream>>>(x, mean, Wl, Wr, bias, gamma, beta,
                                                    (float*)d_out, N);
}

// Round 15
// 150.362 us; speedup vs baseline: 1.2176x; 1.2086x over previous
//
#include <hip/hip_runtime.h>
#include <hip/hip_bf16.h>

#define LN_EPS 1e-5f
#define BSH   7                  // bucket shift: 128 nodes/bucket
#define BNODE 128
#define EPB   8192               // edges per bucket_scatter block
#define CAP   4096               // max edges per bucket stageable in LDS

typedef __attribute__((ext_vector_type(8))) short bf16x8;
typedef __attribute__((ext_vector_type(4))) float floatx4;

// ---------------- CSR prefix build (deg + rowstart) ----------------

__global__ __launch_bounds__(256) void hist_kernel(
    const int* __restrict__ ei, int* __restrict__ deg, int E)
{
    int e = blockIdx.x * 256 + threadIdx.x;
    if (e < E) atomicAdd(&deg[ei[E + e]], 1);
}

__global__ __launch_bounds__(256) void scan1_kernel(
    const int* __restrict__ deg, int* __restrict__ rowstart,
    int* __restrict__ tilesum, int n)
{
    __shared__ int wsum[4];
    int t = threadIdx.x;
    int base = blockIdx.x * 2048 + t * 8;
    int v[8]; int tsum = 0;
    #pragma unroll
    for (int i = 0; i < 8; ++i) { v[i] = (base + i < n) ? deg[base + i] : 0; tsum += v[i]; }
    int lane = t & 63, w = t >> 6;
    int sc = tsum;
    #pragma unroll
    for (int off = 1; off < 64; off <<= 1) {
        int y = __shfl_up(sc, off);
        if (lane >= off) sc += y;
    }
    if (lane == 63) wsum[w] = sc;
    __syncthreads();
    int woff = 0;
    for (int j = 0; j < w; ++j) woff += wsum[j];
    int run = woff + sc - tsum;
    #pragma unroll
    for (int i = 0; i < 8; ++i) { if (base + i < n) rowstart[base + i] = run; run += v[i]; }
    if (t == 255) tilesum[blockIdx.x] = wsum[0] + wsum[1] + wsum[2] + wsum[3];
}

__global__ void scan2_kernel(int* tilesum, int T)
{
    if (blockIdx.x == 0 && threadIdx.x == 0) {
        int run = 0;
        for (int i = 0; i < T; ++i) { int v = tilesum[i]; tilesum[i] = run; run += v; }
    }
}

// also seeds gcursor[b] = rowstart[b*128]
__global__ __launch_bounds__(256) void scan3_kernel(
    int* __restrict__ rowstart, const int* __restrict__ tilesum,
    int* __restrict__ gcursor, int n, int E)
{
    int i = blockIdx.x * 256 + threadIdx.x;
    if (i < n) {
        int v = rowstart[i] + tilesum[i >> 11];
        rowstart[i] = v;
        if ((i & (BNODE - 1)) == 0) gcursor[i >> BSH] = v;
    }
    if (i == 0) rowstart[n] = E;
}

// ---------------- bucket scatter ----------------
__global__ __launch_bounds__(256) void bucket_scatter_kernel(
    const int* __restrict__ ei,
    int* __restrict__ gcursor,
    int* __restrict__ ebuf,
    int E, int NB)
{
    __shared__ int lhist[1024];   // NB = 782 for N = 100k
    __shared__ int lbase[1024];
    __shared__ int lcur[1024];

    int t = threadIdx.x;
    int base = blockIdx.x * EPB;

    for (int b = t; b < NB; b += 256) lhist[b] = 0;
    __syncthreads();

    #pragma unroll 4
    for (int i = 0; i < EPB / 256; ++i) {
        int e = base + i * 256 + t;          // coalesced
        if (e < E) atomicAdd(&lhist[ei[E + e] >> BSH], 1);
    }
    __syncthreads();

    for (int b = t; b < NB; b += 256) {
        int c = lhist[b];
        lbase[b] = c ? atomicAdd(&gcursor[b], c) : 0;
        lcur[b]  = 0;
    }
    __syncthreads();

    #pragma unroll 4
    for (int i = 0; i < EPB / 256; ++i) {
        int e = base + i * 256 + t;
        if (e < E) {
            int src = ei[e];
            int dst = ei[E + e];
            int b   = dst >> BSH;
            int pos = lbase[b] + atomicAdd(&lcur[b], 1);
            ebuf[pos] = src | ((dst & (BNODE - 1)) << 17);
        }
    }
}

// ---------------- csrsort: bucket -> exact CSR order via LDS ----------------
__global__ __launch_bounds__(256) void csrsort_kernel(
    const int* __restrict__ rowstart,
    const int* __restrict__ ebuf,
    int* __restrict__ esrc,
    int N)
{
    __shared__ int rbase[BNODE + 1];
    __shared__ int lcur[BNODE];
    __shared__ int sorted[CAP];

    int t    = threadIdx.x;
    int nb0  = blockIdx.x << BSH;
    int top  = min(nb0 + BNODE, N);
    int nloc = top - nb0;

    for (int i = t; i <= nloc; i += 256) rbase[i] = rowstart[nb0 + i];
    for (int i = t; i < nloc;  i += 256) lcur[i] = 0;
    __syncthreads();

    int s0 = rbase[0], s1 = rbase[nloc];
    int cnt = s1 - s0;

    if (cnt <= CAP) {
        for (int i = s0 + t; i < s1; i += 256) {
            int p = ebuf[i];
            int n = p >> 17;
            int slot = (rbase[n] - s0) + atomicAdd(&lcur[n], 1);
            sorted[slot] = p & 0x1FFFF;
        }
        __syncthreads();
        for (int i = t; i < cnt; i += 256) esrc[s0 + i] = sorted[i];  // coalesced
    } else {
        for (int i = s0 + t; i < s1; i += 256) {
            int p = ebuf[i];
            int n = p >> 17;
            int slot = rbase[n] + atomicAdd(&lcur[n], 1);
            esrc[slot] = p & 0x1FFFF;
        }
    }
}

// ---------------- gather: CSR mean-aggregate (round-3 proven) ----------------
__global__ __launch_bounds__(256) void gather_kernel(
    const float* __restrict__ x,
    const int*   __restrict__ rowstart,
    const int*   __restrict__ esrc,
    float* __restrict__ mean,
    int N)
{
    int tid  = threadIdx.x;
    int lane = tid & 63;
    int g    = lane >> 4;
    int l4   = (lane & 15) * 4;
    int node = blockIdx.x * 4 + (tid >> 6);
    if (node >= N) return;
    int s0 = rowstart[node], s1 = rowstart[node + 1];

    float4 a0 = make_float4(0.f, 0.f, 0.f, 0.f);
    float4 a1 = make_float4(0.f, 0.f, 0.f, 0.f);
    int e = s0 + g;
    for (; e + 4 < s1; e += 8) {
        int sA = esrc[e];
        int sB = esrc[e + 4];
        float4 va = *(const float4*)&x[(size_t)sA * 64 + l4];
        float4 vb = *(const float4*)&x[(size_t)sB * 64 + l4];
        a0.x += va.x; a0.y += va.y; a0.z += va.z; a0.w += va.w;
        a1.x += vb.x; a1.y += vb.y; a1.z += vb.z; a1.w += vb.w;
    }
    if (e < s1) {
        float4 va = *(const float4*)&x[(size_t)esrc[e] * 64 + l4];
        a0.x += va.x; a0.y += va.y; a0.z += va.z; a0.w += va.w;
    }
    a0.x += a1.x; a0.y += a1.y; a0.z += a1.z; a0.w += a1.w;

    a0.x += __shfl_xor(a0.x, 32); a0.y += __shfl_xor(a0.y, 32);
    a0.z += __shfl_xor(a0.z, 32); a0.w += __shfl_xor(a0.w, 32);
    a0.x += __shfl_xor(a0.x, 16); a0.y += __shfl_xor(a0.y, 16);
    a0.z += __shfl_xor(a0.z, 16); a0.w += __shfl_xor(a0.w, 16);

    if (g == 0) {
        float inv = 1.0f / fmaxf((float)(s1 - s0), 1.0f);
        float4 r = make_float4(a0.x * inv, a0.y * inv, a0.z * inv, a0.w * inv);
        *(float4*)&mean[(size_t)node * 64 + l4] = r;
    }
}

// ---------------- MFMA MLP + LayerNorm + ELU ----------------
// r10-r14 showed the s_load VALU-GEMM is capped ~47us by per-chunk scalar
// waits. Replace with matrix cores: per block (64 nodes), C[64x64] =
// A[64x128] @ B[128x64], A = [mean|x] bf16, B = [Wl^T;Wr^T] bf16, f32 accum.
// 4 waves x (4 col-tiles x 4 k-chunks) mfma_f32_16x16x32_bf16. LDS tiles
// stride 136 bf16 (272B: 16B-aligned b128 reads; bank step 68%32=4 -> 2
// lanes/bank = free). B stored transposed (BT[j][k] = rows of Wl/Wr verbatim)
// so both frags read 16B contiguous. C/D layout (m89-verified):
// col=lane&15, row=(lane>>4)*4+reg. LN is in-wave: node's 64 channels live in
// one 16-lane group x 4 ct -> 4x shfl_xor. Precision: bf16 inputs, f32 accum
// (est +0.02-0.03 absmax vs 0.0975 threshold).
__global__ __launch_bounds__(256) void mfma_mlp_kernel(
    const float* __restrict__ x,
    const float* mean,              // aliases out - no restrict
    const float* __restrict__ Wl,
    const float* __restrict__ Wr,
    const float* __restrict__ bias,
    const float* __restrict__ gamma,
    const float* __restrict__ beta,
    float* out,
    int N)
{
    __shared__ short smA[64][136];   // [node][k]  k<64: mean, k>=64: x
    __shared__ short smB[64][136];   // [j][k]     k<64: Wl[j], k>=64: Wr[j]

    int tid  = threadIdx.x;
    int lane = tid & 63;
    int w    = tid >> 6;
    int lo   = lane & 15;
    int hi   = lane >> 4;
    int nbase = blockIdx.x * 64;

    // ---- stage A (mean|x) and B (Wl|Wr rows) as bf16, RNE ----
    #pragma unroll
    for (int it = 0; it < 4; ++it) {
        int slot = tid + it * 256;          // 0..1023 float4 slots
        int row  = slot >> 4;
        int c4   = (slot & 15) * 4;
        int g    = nbase + row;
        size_t roff = (size_t)(g < N ? g : 0) * 64 + c4;
        float4 mv = *(const float4*)&mean[roff];
        float4 xv = *(const float4*)&x[roff];
        float4 wl = *(const float4*)&Wl[slot * 4];   // row=slot>>4=j, col=c4
        float4 wr = *(const float4*)&Wr[slot * 4];

        #define F2BF(f) ((unsigned short)((__float_as_uint(f) + 0x7FFF + \
                        ((__float_as_uint(f) >> 16) & 1)) >> 16))
        uint2 mp, xp, lp, rp;
        mp.x = (unsigned)F2BF(mv.x) | ((unsigned)F2BF(mv.y) << 16);
        mp.y = (unsigned)F2BF(mv.z) | ((unsigned)F2BF(mv.w) << 16);
        xp.x = (unsigned)F2BF(xv.x) | ((unsigned)F2BF(xv.y) << 16);
        xp.y = (unsigned)F2BF(xv.z) | ((unsigned)F2BF(xv.w) << 16);
        lp.x = (unsigned)F2BF(wl.x) | ((unsigned)F2BF(wl.y) << 16);
        lp.y = (unsigned)F2BF(wl.z) | ((unsigned)F2BF(wl.w) << 16);
        rp.x = (unsigned)F2BF(wr.x) | ((unsigned)F2BF(wr.y) << 16);
        rp.y = (unsigned)F2BF(wr.z) | ((unsigned)F2BF(wr.w) << 16);
        #undef F2BF
        *(uint2*)&smA[row][c4]      = mp;
        *(uint2*)&smA[row][64 + c4] = xp;
        *(uint2*)&smB[row][c4]      = lp;   // row=j
        *(uint2*)&smB[row][64 + c4] = rp;
    }
    __syncthreads();   // all mean reads done -> out writes legal (aliasing)

    // ---- fragments & MFMA ----
    bf16x8 a0 = *(const bf16x8*)&smA[w * 16 + lo][ 0 + hi * 8];
    bf16x8 a1 = *(const bf16x8*)&smA[w * 16 + lo][32 + hi * 8];
    bf16x8 a2 = *(const bf16x8*)&smA[w * 16 + lo][64 + hi * 8];
    bf16x8 a3 = *(const bf16x8*)&smA[w * 16 + lo][96 + hi * 8];

    floatx4 c[4];
    #pragma unroll
    for (int ct = 0; ct < 4; ++ct) {
        float b = bias[ct * 16 + lo];
        c[ct] = (floatx4){b, b, b, b};
    }

    #pragma unroll
    for (int ct = 0; ct < 4; ++ct) {
        int j = ct * 16 + lo;
        bf16x8 b0 = *(const bf16x8*)&smB[j][ 0 + hi * 8];
        bf16x8 b1 = *(const bf16x8*)&smB[j][32 + hi * 8];
        bf16x8 b2 = *(const bf16x8*)&smB[j][64 + hi * 8];
        bf16x8 b3 = *(const bf16x8*)&smB[j][96 + hi * 8];
        c[ct] = __builtin_amdgcn_mfma_f32_16x16x32_bf16(a0, b0, c[ct], 0, 0, 0);
        c[ct] = __builtin_amdgcn_mfma_f32_16x16x32_bf16(a1, b1, c[ct], 0, 0, 0);
        c[ct] = __builtin_amdgcn_mfma_f32_16x16x32_bf16(a2, b2, c[ct], 0, 0, 0);
        c[ct] = __builtin_amdgcn_mfma_f32_16x16x32_bf16(a3, b3, c[ct], 0, 0, 0);
    }

    // ---- LayerNorm (in-wave: 16-lane group holds a node's 64 channels) ----
    float s[4], q[4];
    #pragma unroll
    for (int p = 0; p < 4; ++p) {
        s[p] = c[0][p] + c[1][p] + c[2][p] + c[3][p];
        q[p] = c[0][p]*c[0][p] + c[1][p]*c[1][p]
             + c[2][p]*c[2][p] + c[3][p]*c[3][p];
        #pragma unroll
        for (int off = 1; off < 16; off <<= 1) {
            s[p] += __shfl_xor(s[p], off);
            q[p] += __shfl_xor(q[p], off);
        }
    }

    #pragma unroll
    for (int p = 0; p < 4; ++p) {
        int node = nbase + w * 16 + hi * 4 + p;   // C row = hi*4+p
        if (node >= N) continue;
        float mu  = s[p] * (1.0f / 64.0f);
        float var = q[p] * (1.0f / 64.0f) - mu * mu;
        float rr  = rsqrtf(var + LN_EPS);
        #pragma unroll
        for (int ct = 0; ct < 4; ++ct) {
            int col = ct * 16 + lo;
            float hn = (c[ct][p] - mu) * rr * gamma[col] + beta[col];
            hn = hn > 0.f ? hn : __expf(hn) - 1.0f;
            out[(size_t)node * 64 + col] = hn;
        }
    }
}

extern "C" void kernel_launch(void* const* d_in, const int* in_sizes, int n_in,
                              void* d_out, int out_size, void* d_ws, size_t ws_size,
                              hipStream_t stream) {
    const float* x     = (const float*)d_in[0];
    const int*   ei    = (const int*)  d_in[1];
    const float* Wl    = (const float*)d_in[2];
    const float* Wr    = (const float*)d_in[3];
    const float* bias  = (const float*)d_in[4];
    const float* gamma = (const float*)d_in[5];
    const float* beta  = (const float*)d_in[6];

    int N  = in_sizes[0] / 64;
    int E  = in_sizes[1] / 2;
    int NB = (N + BNODE - 1) >> BSH;       // 782 buckets

    int* deg      = (int*)d_ws;            // N
    int* rowstart = deg + N;               // N+1
    int* tilesum  = rowstart + (N + 1);    // <=64
    int* gcursor  = tilesum + 64;          // NB
    int* ebuf     = gcursor + NB;          // E (packed src | dstlocal<<17)
    int* esrc     = ebuf + E;              // E (CSR-ordered src)
    float* mean   = (float*)d_out;         // N*64; mfma reads its rows pre-barrier

    hipMemsetAsync(deg, 0, (size_t)N * sizeof(int), stream);

    hist_kernel<<<(E + 255) / 256, 256, 0, stream>>>(ei, deg, E);

    int T = (N + 2047) / 2048;
    scan1_kernel<<<T, 256, 0, stream>>>(deg, rowstart, tilesum, N);
    scan2_kernel<<<1, 64, 0, stream>>>(tilesum, T);
    scan3_kernel<<<(N + 255) / 256, 256, 0, stream>>>(rowstart, tilesum, gcursor, N, E);

    bucket_scatter_kernel<<<(E + EPB - 1) / EPB, 256, 0, stream>>>(ei, gcursor,
                                                                   ebuf, E, NB);

    csrsort_kernel<<<NB, 256, 0, stream>>>(rowstart, ebuf, esrc, N);

    gather_kernel<<<(N + 3) / 4, 256, 0, stream>>>(x, rowstart, esrc, mean, N);

    mfma_mlp_kernel<<<(N + 63) / 64, 256, 0, stream>>>(x, mean, Wl, Wr, bias,
                                                       gamma, beta,
                                                       (float*)d_out, N);
}

// Round 16
// 144.797 us; speedup vs baseline: 1.2644x; 1.0384x over previous
//
#include <hip/hip_runtime.h>
#include <hip/hip_bf16.h>

#define LN_EPS 1e-5f
#define BSH   7                  // bucket shift: 128 nodes/bucket
#define BNODE 128
#define EPB   8192               // edges per bucket_scatter block
#define CAP   4096               // max edges per bucket stageable in LDS

typedef __attribute__((ext_vector_type(8))) short bf16x8;
typedef __attribute__((ext_vector_type(4))) float floatx4;

#define F2BF(f) ((unsigned short)((__float_as_uint(f) + 0x7FFF + \
                ((__float_as_uint(f) >> 16) & 1)) >> 16))

// ---------------- x -> bf16 (halves gather's row-read volume) ----------------
__global__ __launch_bounds__(256) void cvt_kernel(
    const float* __restrict__ x, unsigned short* __restrict__ xb, int n64)
{
    int i = (blockIdx.x * 256 + threadIdx.x) * 8;
    if (i >= n64) return;
    float4 a = *(const float4*)&x[i];
    float4 b = *(const float4*)&x[i + 4];
    uint4 o;
    o.x = (unsigned)F2BF(a.x) | ((unsigned)F2BF(a.y) << 16);
    o.y = (unsigned)F2BF(a.z) | ((unsigned)F2BF(a.w) << 16);
    o.z = (unsigned)F2BF(b.x) | ((unsigned)F2BF(b.y) << 16);
    o.w = (unsigned)F2BF(b.z) | ((unsigned)F2BF(b.w) << 16);
    *(uint4*)&xb[i] = o;
}

// ---------------- CSR prefix build (deg + rowstart) ----------------

__global__ __launch_bounds__(256) void hist_kernel(
    const int* __restrict__ ei, int* __restrict__ deg, int E)
{
    int e = blockIdx.x * 256 + threadIdx.x;
    if (e < E) atomicAdd(&deg[ei[E + e]], 1);
}

__global__ __launch_bounds__(256) void scan1_kernel(
    const int* __restrict__ deg, int* __restrict__ rowstart,
    int* __restrict__ tilesum, int n)
{
    __shared__ int wsum[4];
    int t = threadIdx.x;
    int base = blockIdx.x * 2048 + t * 8;
    int v[8]; int tsum = 0;
    #pragma unroll
    for (int i = 0; i < 8; ++i) { v[i] = (base + i < n) ? deg[base + i] : 0; tsum += v[i]; }
    int lane = t & 63, w = t >> 6;
    int sc = tsum;
    #pragma unroll
    for (int off = 1; off < 64; off <<= 1) {
        int y = __shfl_up(sc, off);
        if (lane >= off) sc += y;
    }
    if (lane == 63) wsum[w] = sc;
    __syncthreads();
    int woff = 0;
    for (int j = 0; j < w; ++j) woff += wsum[j];
    int run = woff + sc - tsum;
    #pragma unroll
    for (int i = 0; i < 8; ++i) { if (base + i < n) rowstart[base + i] = run; run += v[i]; }
    if (t == 255) tilesum[blockIdx.x] = wsum[0] + wsum[1] + wsum[2] + wsum[3];
}

// scan2 folded in: every block wave-scans the <=64 tile sums redundantly.
// Also seeds gcursor[b] = rowstart[b*128].
__global__ __launch_bounds__(256) void scan3_kernel(
    int* __restrict__ rowstart, const int* __restrict__ tilesum,
    int* __restrict__ gcursor, int n, int E, int T)
{
    __shared__ int stile[64];
    int t = threadIdx.x;
    if (t < 64) {
        int v = (t < T) ? tilesum[t] : 0;
        int sc = v;
        #pragma unroll
        for (int off = 1; off < 64; off <<= 1) {
            int y = __shfl_up(sc, off);
            if (t >= off) sc += y;
        }
        stile[t] = sc - v;    // exclusive prefix
    }
    __syncthreads();
    int i = blockIdx.x * 256 + t;
    if (i < n) {
        int v = rowstart[i] + stile[i >> 11];
        rowstart[i] = v;
        if ((i & (BNODE - 1)) == 0) gcursor[i >> BSH] = v;
    }
    if (i == 0) rowstart[n] = E;
}

// ---------------- bucket scatter ----------------
__global__ __launch_bounds__(256) void bucket_scatter_kernel(
    const int* __restrict__ ei,
    int* __restrict__ gcursor,
    int* __restrict__ ebuf,
    int E, int NB)
{
    __shared__ int lhist[1024];   // NB = 782 for N = 100k
    __shared__ int lbase[1024];
    __shared__ int lcur[1024];

    int t = threadIdx.x;
    int base = blockIdx.x * EPB;

    for (int b = t; b < NB; b += 256) lhist[b] = 0;
    __syncthreads();

    #pragma unroll 4
    for (int i = 0; i < EPB / 256; ++i) {
        int e = base + i * 256 + t;          // coalesced
        if (e < E) atomicAdd(&lhist[ei[E + e] >> BSH], 1);
    }
    __syncthreads();

    for (int b = t; b < NB; b += 256) {
        int c = lhist[b];
        lbase[b] = c ? atomicAdd(&gcursor[b], c) : 0;
        lcur[b]  = 0;
    }
    __syncthreads();

    #pragma unroll 4
    for (int i = 0; i < EPB / 256; ++i) {
        int e = base + i * 256 + t;
        if (e < E) {
            int src = ei[e];
            int dst = ei[E + e];
            int b   = dst >> BSH;
            int pos = lbase[b] + atomicAdd(&lcur[b], 1);
            ebuf[pos] = src | ((dst & (BNODE - 1)) << 17);
        }
    }
}

// ---------------- csrsort: bucket -> exact CSR order via LDS ----------------
__global__ __launch_bounds__(256) void csrsort_kernel(
    const int* __restrict__ rowstart,
    const int* __restrict__ ebuf,
    int* __restrict__ esrc,
    int N)
{
    __shared__ int rbase[BNODE + 1];
    __shared__ int lcur[BNODE];
    __shared__ int sorted[CAP];

    int t    = threadIdx.x;
    int nb0  = blockIdx.x << BSH;
    int top  = min(nb0 + BNODE, N);
    int nloc = top - nb0;

    for (int i = t; i <= nloc; i += 256) rbase[i] = rowstart[nb0 + i];
    for (int i = t; i < nloc;  i += 256) lcur[i] = 0;
    __syncthreads();

    int s0 = rbase[0], s1 = rbase[nloc];
    int cnt = s1 - s0;

    if (cnt <= CAP) {
        for (int i = s0 + t; i < s1; i += 256) {
            int p = ebuf[i];
            int n = p >> 17;
            int slot = (rbase[n] - s0) + atomicAdd(&lcur[n], 1);
            sorted[slot] = p & 0x1FFFF;
        }
        __syncthreads();
        for (int i = t; i < cnt; i += 256) esrc[s0 + i] = sorted[i];  // coalesced
    } else {
        for (int i = s0 + t; i < s1; i += 256) {
            int p = ebuf[i];
            int n = p >> 17;
            int slot = rbase[n] + atomicAdd(&lcur[n], 1);
            esrc[slot] = p & 0x1FFFF;
        }
    }
}

// ---------------- gather: CSR mean-aggregate, bf16 rows ----------------
// One node per wave; 4 edge-groups x 16 lanes x 8B (uint2 = 4 bf16) = 128B
// per row load. Halves the r15 line-transfer volume (the 46us plateau was
// L2/L3 fabric volume on random 256B f32 rows). Convert bf16->f32 via
// shift/mask (2 VALU per elem), accumulate f32, reduce across groups.
__global__ __launch_bounds__(256) void gather_kernel(
    const unsigned short* __restrict__ xb,
    const int*   __restrict__ rowstart,
    const int*   __restrict__ esrc,
    float* __restrict__ mean,
    int N)
{
    int tid  = threadIdx.x;
    int lane = tid & 63;
    int g    = lane >> 4;
    int sub  = lane & 15;
    int node = blockIdx.x * 4 + (tid >> 6);
    if (node >= N) return;
    int s0 = rowstart[node], s1 = rowstart[node + 1];

    float a0 = 0.f, a1 = 0.f, a2 = 0.f, a3 = 0.f;
    float b0 = 0.f, b1 = 0.f, b2 = 0.f, b3 = 0.f;
    int e = s0 + g;
    for (; e + 4 < s1; e += 8) {
        int sA = esrc[e];
        int sB = esrc[e + 4];
        uint2 va = *(const uint2*)&xb[(size_t)sA * 64 + sub * 4];
        uint2 vb = *(const uint2*)&xb[(size_t)sB * 64 + sub * 4];
        a0 += __uint_as_float(va.x << 16);
        a1 += __uint_as_float(va.x & 0xFFFF0000u);
        a2 += __uint_as_float(va.y << 16);
        a3 += __uint_as_float(va.y & 0xFFFF0000u);
        b0 += __uint_as_float(vb.x << 16);
        b1 += __uint_as_float(vb.x & 0xFFFF0000u);
        b2 += __uint_as_float(vb.y << 16);
        b3 += __uint_as_float(vb.y & 0xFFFF0000u);
    }
    if (e < s1) {
        uint2 va = *(const uint2*)&xb[(size_t)esrc[e] * 64 + sub * 4];
        a0 += __uint_as_float(va.x << 16);
        a1 += __uint_as_float(va.x & 0xFFFF0000u);
        a2 += __uint_as_float(va.y << 16);
        a3 += __uint_as_float(va.y & 0xFFFF0000u);
    }
    a0 += b0; a1 += b1; a2 += b2; a3 += b3;

    a0 += __shfl_xor(a0, 32); a1 += __shfl_xor(a1, 32);
    a2 += __shfl_xor(a2, 32); a3 += __shfl_xor(a3, 32);
    a0 += __shfl_xor(a0, 16); a1 += __shfl_xor(a1, 16);
    a2 += __shfl_xor(a2, 16); a3 += __shfl_xor(a3, 16);

    if (g == 0) {
        float inv = 1.0f / fmaxf((float)(s1 - s0), 1.0f);
        float4 r = make_float4(a0 * inv, a1 * inv, a2 * inv, a3 * inv);
        *(float4*)&mean[(size_t)node * 64 + sub * 4] = r;   // 16 lanes x 16B
    }
}

// ---------------- MFMA MLP + LayerNorm + ELU (round-15 proven) ----------------
// C[64x64] = A[64x128] @ B[128x64] per block; A = [mean|x] bf16 (x-half staged
// straight from xb, no cvt), B = [Wl^T;Wr^T] bf16, f32 accum. LDS stride 136
// (272B: 16B-aligned b128; 2 lanes/bank = free). C/D: col=lane&15,
// row=(lane>>4)*4+reg (m89-verified). LN in-wave via 16-lane shfl groups.
__global__ __launch_bounds__(256) void mfma_mlp_kernel(
    const unsigned short* __restrict__ xb,
    const float* mean,              // aliases out - no restrict
    const float* __restrict__ Wl,
    const float* __restrict__ Wr,
    const float* __restrict__ bias,
    const float* __restrict__ gamma,
    const float* __restrict__ beta,
    float* out,
    int N)
{
    __shared__ short smA[64][136];   // [node][k]  k<64: mean, k>=64: x
    __shared__ short smB[64][136];   // [j][k]     k<64: Wl[j], k>=64: Wr[j]

    int tid  = threadIdx.x;
    int lane = tid & 63;
    int w    = tid >> 6;
    int lo   = lane & 15;
    int hi   = lane >> 4;
    int nbase = blockIdx.x * 64;

    // mean (f32 -> bf16) + weights (f32 -> bf16)
    #pragma unroll
    for (int it = 0; it < 4; ++it) {
        int slot = tid + it * 256;          // 0..1023 float4 slots
        int row  = slot >> 4;
        int c4   = (slot & 15) * 4;
        int g    = nbase + row;
        size_t roff = (size_t)(g < N ? g : 0) * 64 + c4;
        float4 mv = *(const float4*)&mean[roff];
        float4 wl = *(const float4*)&Wl[slot * 4];
        float4 wr = *(const float4*)&Wr[slot * 4];
        uint2 mp, lp, rp;
        mp.x = (unsigned)F2BF(mv.x) | ((unsigned)F2BF(mv.y) << 16);
        mp.y = (unsigned)F2BF(mv.z) | ((unsigned)F2BF(mv.w) << 16);
        lp.x = (unsigned)F2BF(wl.x) | ((unsigned)F2BF(wl.y) << 16);
        lp.y = (unsigned)F2BF(wl.z) | ((unsigned)F2BF(wl.w) << 16);
        rp.x = (unsigned)F2BF(wr.x) | ((unsigned)F2BF(wr.y) << 16);
        rp.y = (unsigned)F2BF(wr.z) | ((unsigned)F2BF(wr.w) << 16);
        *(uint2*)&smA[row][c4]      = mp;
        *(uint2*)&smB[row][c4]      = lp;   // row=j
        *(uint2*)&smB[row][64 + c4] = rp;
    }
    // x-half: copy bf16 rows verbatim (16B chunks, coalesced)
    #pragma unroll
    for (int it = 0; it < 2; ++it) {
        int s   = tid + it * 256;           // 0..511 slots of 8 bf16
        int row = s >> 3;
        int o8  = (s & 7) * 8;
        int g   = nbase + row;
        uint4 v = *(const uint4*)&xb[(size_t)(g < N ? g : 0) * 64 + o8];
        *(uint4*)&smA[row][64 + o8] = v;
    }
    __syncthreads();   // all mean reads done -> out writes legal (aliasing)

    bf16x8 a0 = *(const bf16x8*)&smA[w * 16 + lo][ 0 + hi * 8];
    bf16x8 a1 = *(const bf16x8*)&smA[w * 16 + lo][32 + hi * 8];
    bf16x8 a2 = *(const bf16x8*)&smA[w * 16 + lo][64 + hi * 8];
    bf16x8 a3 = *(const bf16x8*)&smA[w * 16 + lo][96 + hi * 8];

    floatx4 c[4];
    #pragma unroll
    for (int ct = 0; ct < 4; ++ct) {
        float b = bias[ct * 16 + lo];
        c[ct] = (floatx4){b, b, b, b};
    }

    #pragma unroll
    for (int ct = 0; ct < 4; ++ct) {
        int j = ct * 16 + lo;
        bf16x8 b0 = *(const bf16x8*)&smB[j][ 0 + hi * 8];
        bf16x8 b1 = *(const bf16x8*)&smB[j][32 + hi * 8];
        bf16x8 b2 = *(const bf16x8*)&smB[j][64 + hi * 8];
        bf16x8 b3 = *(const bf16x8*)&smB[j][96 + hi * 8];
        c[ct] = __builtin_amdgcn_mfma_f32_16x16x32_bf16(a0, b0, c[ct], 0, 0, 0);
        c[ct] = __builtin_amdgcn_mfma_f32_16x16x32_bf16(a1, b1, c[ct], 0, 0, 0);
        c[ct] = __builtin_amdgcn_mfma_f32_16x16x32_bf16(a2, b2, c[ct], 0, 0, 0);
        c[ct] = __builtin_amdgcn_mfma_f32_16x16x32_bf16(a3, b3, c[ct], 0, 0, 0);
    }

    float s[4], q[4];
    #pragma unroll
    for (int p = 0; p < 4; ++p) {
        s[p] = c[0][p] + c[1][p] + c[2][p] + c[3][p];
        q[p] = c[0][p]*c[0][p] + c[1][p]*c[1][p]
             + c[2][p]*c[2][p] + c[3][p]*c[3][p];
        #pragma unroll
        for (int off = 1; off < 16; off <<= 1) {
            s[p] += __shfl_xor(s[p], off);
            q[p] += __shfl_xor(q[p], off);
        }
    }

    #pragma unroll
    for (int p = 0; p < 4; ++p) {
        int node = nbase + w * 16 + hi * 4 + p;   // C row = hi*4+p
        if (node >= N) continue;
        float mu  = s[p] * (1.0f / 64.0f);
        float var = q[p] * (1.0f / 64.0f) - mu * mu;
        float rr  = rsqrtf(var + LN_EPS);
        #pragma unroll
        for (int ct = 0; ct < 4; ++ct) {
            int col = ct * 16 + lo;
            float hn = (c[ct][p] - mu) * rr * gamma[col] + beta[col];
            hn = hn > 0.f ? hn : __expf(hn) - 1.0f;
            out[(size_t)node * 64 + col] = hn;
        }
    }
}

extern "C" void kernel_launch(void* const* d_in, const int* in_sizes, int n_in,
                              void* d_out, int out_size, void* d_ws, size_t ws_size,
                              hipStream_t stream) {
    const float* x     = (const float*)d_in[0];
    const int*   ei    = (const int*)  d_in[1];
    const float* Wl    = (const float*)d_in[2];
    const float* Wr    = (const float*)d_in[3];
    const float* bias  = (const float*)d_in[4];
    const float* gamma = (const float*)d_in[5];
    const float* beta  = (const float*)d_in[6];

    int N  = in_sizes[0] / 64;
    int E  = in_sizes[1] / 2;
    int NB = (N + BNODE - 1) >> BSH;       // 782 buckets

    unsigned short* xb = (unsigned short*)d_ws;        // N*64 bf16 (16B-aligned)
    int* deg      = (int*)(xb + (size_t)N * 64);       // N
    int* rowstart = deg + N;               // N+1
    int* tilesum  = rowstart + (N + 1);    // <=64
    int* gcursor  = tilesum + 64;          // NB
    int* ebuf     = gcursor + NB;          // E (packed src | dstlocal<<17)
    int* esrc     = ebuf + E;              // E (CSR-ordered src)
    float* mean   = (float*)d_out;         // N*64; mfma reads its rows pre-barrier

    hipMemsetAsync(deg, 0, (size_t)N * sizeof(int), stream);

    cvt_kernel<<<(N * 64 + 2047) / 2048, 256, 0, stream>>>(x, xb, N * 64);

    hist_kernel<<<(E + 255) / 256, 256, 0, stream>>>(ei, deg, E);

    int T = (N + 2047) / 2048;
    scan1_kernel<<<T, 256, 0, stream>>>(deg, rowstart, tilesum, N);
    scan3_kernel<<<(N + 255) / 256, 256, 0, stream>>>(rowstart, tilesum, gcursor,
                                                      N, E, T);

    bucket_scatter_kernel<<<(E + EPB - 1) / EPB, 256, 0, stream>>>(ei, gcursor,
                                                                   ebuf, E, NB);

    csrsort_kernel<<<NB, 256, 0, stream>>>(rowstart, ebuf, esrc, N);

    gather_kernel<<<(N + 3) / 4, 256, 0, stream>>>(xb, rowstart, esrc, mean, N);

    mfma_mlp_kernel<<<(N + 63) / 64, 256, 0, stream>>>(xb, mean, Wl, Wr, bias,
                                                       gamma, beta,
                                                       (float*)d_out, N);
}

// Round 17
// 103.901 us; speedup vs baseline: 1.7620x; 1.3936x over previous
//
#include <hip/hip_runtime.h>
#include <hip/hip_bf16.h>

#define LN_EPS 1e-5f
#define BSH   7                  // bucket shift: 128 nodes/bucket
#define BNODE 128
#define EPB   8192               // edges per bucket block
#define CAP   4096               // max edges per bucket stageable in LDS

typedef __attribute__((ext_vector_type(8))) short bf16x8;
typedef __attribute__((ext_vector_type(4))) float floatx4;

#define F2BF(f) ((unsigned short)((__float_as_uint(f) + 0x7FFF + \
                ((__float_as_uint(f) >> 16) & 1)) >> 16))

// ---------------- x -> bf16 (+ block 0 zeroes bcount: replaces memset) ----------------
__global__ __launch_bounds__(256) void cvt_kernel(
    const float* __restrict__ x, unsigned short* __restrict__ xb, int n64,
    int* __restrict__ bcount, int NB)
{
    if (blockIdx.x == 0) {
        for (int i = threadIdx.x; i < NB; i += 256) bcount[i] = 0;
    }
    int i = (blockIdx.x * 256 + threadIdx.x) * 8;
    if (i >= n64) return;
    float4 a = *(const float4*)&x[i];
    float4 b = *(const float4*)&x[i + 4];
    uint4 o;
    o.x = (unsigned)F2BF(a.x) | ((unsigned)F2BF(a.y) << 16);
    o.y = (unsigned)F2BF(a.z) | ((unsigned)F2BF(a.w) << 16);
    o.z = (unsigned)F2BF(b.x) | ((unsigned)F2BF(b.y) << 16);
    o.w = (unsigned)F2BF(b.z) | ((unsigned)F2BF(b.w) << 16);
    *(uint4*)&xb[i] = o;
}

// ---------------- bucket histogram: LDS -> 1 atomic per bucket per block ----------------
// Replaces the 1M-random-atomic hist_kernel (42.9us: device-scope lines
// ping-ponging across 8 XCD L2s). 96k aggregated atomics instead.
__global__ __launch_bounds__(256) void bucket_hist_kernel(
    const int* __restrict__ ei, int* __restrict__ bcount, int E, int NB)
{
    __shared__ int lhist[1024];
    int t = threadIdx.x;
    int base = blockIdx.x * EPB;
    for (int b = t; b < NB; b += 256) lhist[b] = 0;
    __syncthreads();
    #pragma unroll 4
    for (int i = 0; i < EPB / 256; ++i) {
        int e = base + i * 256 + t;
        if (e < E) atomicAdd(&lhist[ei[E + e] >> BSH], 1);
    }
    __syncthreads();
    for (int b = t; b < NB; b += 256) {
        int c = lhist[b];
        if (c) atomicAdd(&bcount[b], c);
    }
}

// ---------------- bucket scan: 1 block, exclusive scan of <=1024 buckets ----------------
__global__ __launch_bounds__(256) void bucket_scan_kernel(
    const int* __restrict__ bcount, int* __restrict__ bbase,
    int* __restrict__ gcursor, int NB, int E)
{
    __shared__ int wsum[4];
    int t = threadIdx.x;
    int v[4]; int tsum = 0;
    #pragma unroll
    for (int i = 0; i < 4; ++i) {
        int idx = t * 4 + i;
        v[i] = (idx < NB) ? bcount[idx] : 0;
        tsum += v[i];
    }
    int lane = t & 63, w = t >> 6;
    int sc = tsum;
    #pragma unroll
    for (int off = 1; off < 64; off <<= 1) {
        int y = __shfl_up(sc, off);
        if (lane >= off) sc += y;
    }
    if (lane == 63) wsum[w] = sc;
    __syncthreads();
    int woff = 0;
    for (int j = 0; j < w; ++j) woff += wsum[j];
    int run = woff + sc - tsum;
    #pragma unroll
    for (int i = 0; i < 4; ++i) {
        int idx = t * 4 + i;
        if (idx < NB) { bbase[idx] = run; gcursor[idx] = run; }
        run += v[i];
    }
    if (t == 255) bbase[NB] = E;
}

// ---------------- bucket scatter (round-10 proven) ----------------
__global__ __launch_bounds__(256) void bucket_scatter_kernel(
    const int* __restrict__ ei,
    int* __restrict__ gcursor,
    int* __restrict__ ebuf,
    int E, int NB)
{
    __shared__ int lhist[1024];
    __shared__ int lbase[1024];
    __shared__ int lcur[1024];

    int t = threadIdx.x;
    int base = blockIdx.x * EPB;

    for (int b = t; b < NB; b += 256) lhist[b] = 0;
    __syncthreads();

    #pragma unroll 4
    for (int i = 0; i < EPB / 256; ++i) {
        int e = base + i * 256 + t;          // coalesced
        if (e < E) atomicAdd(&lhist[ei[E + e] >> BSH], 1);
    }
    __syncthreads();

    for (int b = t; b < NB; b += 256) {
        int c = lhist[b];
        lbase[b] = c ? atomicAdd(&gcursor[b], c) : 0;
        lcur[b]  = 0;
    }
    __syncthreads();

    #pragma unroll 4
    for (int i = 0; i < EPB / 256; ++i) {
        int e = base + i * 256 + t;
        if (e < E) {
            int src = ei[e];
            int dst = ei[E + e];
            int b   = dst >> BSH;
            int pos = lbase[b] + atomicAdd(&lcur[b], 1);
            ebuf[pos] = src | ((dst & (BNODE - 1)) << 17);
        }
    }
}

// ---------------- csrsort v2: per-node count + scan + rowstart + sort ----------------
// One block per bucket. Counts its 128 nodes in LDS (private atomics), scans
// them in one wave (2 elems/lane shfl), WRITES rowstart itself (bbase + local
// prefix; block boundaries coincide: rowstart[nb0+128] from block b equals
// block b+1's rowstart[nb0']; last block emits rowstart[N]=E), then sorts the
// bucket in LDS and writes esrc coalesced. Eliminates hist/scan1/scan3.
__global__ __launch_bounds__(256) void csrsort_kernel(
    const int* __restrict__ bbase,
    const int* __restrict__ ebuf,
    int* __restrict__ esrc,
    int* __restrict__ rowstart,
    int N)
{
    __shared__ int lcnt[BNODE];
    __shared__ int lpre[BNODE + 1];
    __shared__ int lcur[BNODE];
    __shared__ int sorted[CAP];

    int t    = threadIdx.x;
    int b    = blockIdx.x;
    int nb0  = b << BSH;
    int nloc = min(BNODE, N - nb0);
    int s0   = bbase[b];
    int s1   = bbase[b + 1];
    int cnt  = s1 - s0;

    if (t < BNODE) { lcnt[t] = 0; lcur[t] = 0; }
    __syncthreads();

    for (int i = s0 + t; i < s1; i += 256)
        atomicAdd(&lcnt[(unsigned)ebuf[i] >> 17], 1);
    __syncthreads();

    if (t < 64) {   // wave 0: scan 128 counts, 2 per lane
        int v0 = lcnt[2 * t], v1 = lcnt[2 * t + 1];
        int p = v0 + v1, sc = p;
        #pragma unroll
        for (int off = 1; off < 64; off <<= 1) {
            int y = __shfl_up(sc, off);
            if (t >= off) sc += y;
        }
        int excl = sc - p;
        lpre[2 * t]     = excl;
        lpre[2 * t + 1] = excl + v0;
        if (t == 63) lpre[BNODE] = excl + p;   // == cnt
    }
    __syncthreads();

    if (t <= nloc) rowstart[nb0 + t] = s0 + lpre[t];

    if (cnt <= CAP) {
        for (int i = s0 + t; i < s1; i += 256) {
            int p = ebuf[i];
            int n = (unsigned)p >> 17;
            int slot = lpre[n] + atomicAdd(&lcur[n], 1);
            sorted[slot] = p & 0x1FFFF;
        }
        __syncthreads();
        for (int i = t; i < cnt; i += 256) esrc[s0 + i] = sorted[i];  // coalesced
    } else {
        for (int i = s0 + t; i < s1; i += 256) {
            int p = ebuf[i];
            int n = (unsigned)p >> 17;
            int slot = s0 + lpre[n] + atomicAdd(&lcur[n], 1);
            esrc[slot] = p & 0x1FFFF;
        }
    }
}

// ---------------- gather: CSR mean-aggregate, bf16 rows (round-16 proven) ----------------
__global__ __launch_bounds__(256) void gather_kernel(
    const unsigned short* __restrict__ xb,
    const int*   __restrict__ rowstart,
    const int*   __restrict__ esrc,
    float* __restrict__ mean,
    int N)
{
    int tid  = threadIdx.x;
    int lane = tid & 63;
    int g    = lane >> 4;
    int sub  = lane & 15;
    int node = blockIdx.x * 4 + (tid >> 6);
    if (node >= N) return;
    int s0 = rowstart[node], s1 = rowstart[node + 1];

    float a0 = 0.f, a1 = 0.f, a2 = 0.f, a3 = 0.f;
    float b0 = 0.f, b1 = 0.f, b2 = 0.f, b3 = 0.f;
    int e = s0 + g;
    for (; e + 4 < s1; e += 8) {
        int sA = esrc[e];
        int sB = esrc[e + 4];
        uint2 va = *(const uint2*)&xb[(size_t)sA * 64 + sub * 4];
        uint2 vb = *(const uint2*)&xb[(size_t)sB * 64 + sub * 4];
        a0 += __uint_as_float(va.x << 16);
        a1 += __uint_as_float(va.x & 0xFFFF0000u);
        a2 += __uint_as_float(va.y << 16);
        a3 += __uint_as_float(va.y & 0xFFFF0000u);
        b0 += __uint_as_float(vb.x << 16);
        b1 += __uint_as_float(vb.x & 0xFFFF0000u);
        b2 += __uint_as_float(vb.y << 16);
        b3 += __uint_as_float(vb.y & 0xFFFF0000u);
    }
    if (e < s1) {
        uint2 va = *(const uint2*)&xb[(size_t)esrc[e] * 64 + sub * 4];
        a0 += __uint_as_float(va.x << 16);
        a1 += __uint_as_float(va.x & 0xFFFF0000u);
        a2 += __uint_as_float(va.y << 16);
        a3 += __uint_as_float(va.y & 0xFFFF0000u);
    }
    a0 += b0; a1 += b1; a2 += b2; a3 += b3;

    a0 += __shfl_xor(a0, 32); a1 += __shfl_xor(a1, 32);
    a2 += __shfl_xor(a2, 32); a3 += __shfl_xor(a3, 32);
    a0 += __shfl_xor(a0, 16); a1 += __shfl_xor(a1, 16);
    a2 += __shfl_xor(a2, 16); a3 += __shfl_xor(a3, 16);

    if (g == 0) {
        float inv = 1.0f / fmaxf((float)(s1 - s0), 1.0f);
        float4 r = make_float4(a0 * inv, a1 * inv, a2 * inv, a3 * inv);
        *(float4*)&mean[(size_t)node * 64 + sub * 4] = r;   // 16 lanes x 16B
    }
}

// ---------------- MFMA MLP + LayerNorm + ELU (round-15/16 proven) ----------------
__global__ __launch_bounds__(256) void mfma_mlp_kernel(
    const unsigned short* __restrict__ xb,
    const float* mean,              // aliases out - no restrict
    const float* __restrict__ Wl,
    const float* __restrict__ Wr,
    const float* __restrict__ bias,
    const float* __restrict__ gamma,
    const float* __restrict__ beta,
    float* out,
    int N)
{
    __shared__ short smA[64][136];   // [node][k]  k<64: mean, k>=64: x
    __shared__ short smB[64][136];   // [j][k]     k<64: Wl[j], k>=64: Wr[j]

    int tid  = threadIdx.x;
    int lane = tid & 63;
    int w    = tid >> 6;
    int lo   = lane & 15;
    int hi   = lane >> 4;
    int nbase = blockIdx.x * 64;

    #pragma unroll
    for (int it = 0; it < 4; ++it) {
        int slot = tid + it * 256;          // 0..1023 float4 slots
        int row  = slot >> 4;
        int c4   = (slot & 15) * 4;
        int g    = nbase + row;
        size_t roff = (size_t)(g < N ? g : 0) * 64 + c4;
        float4 mv = *(const float4*)&mean[roff];
        float4 wl = *(const float4*)&Wl[slot * 4];
        float4 wr = *(const float4*)&Wr[slot * 4];
        uint2 mp, lp, rp;
        mp.x = (unsigned)F2BF(mv.x) | ((unsigned)F2BF(mv.y) << 16);
        mp.y = (unsigned)F2BF(mv.z) | ((unsigned)F2BF(mv.w) << 16);
        lp.x = (unsigned)F2BF(wl.x) | ((unsigned)F2BF(wl.y) << 16);
        lp.y = (unsigned)F2BF(wl.z) | ((unsigned)F2BF(wl.w) << 16);
        rp.x = (unsigned)F2BF(wr.x) | ((unsigned)F2BF(wr.y) << 16);
        rp.y = (unsigned)F2BF(wr.z) | ((unsigned)F2BF(wr.w) << 16);
        *(uint2*)&smA[row][c4]      = mp;
        *(uint2*)&smB[row][c4]      = lp;   // row=j
        *(uint2*)&smB[row][64 + c4] = rp;
    }
    #pragma unroll
    for (int it = 0; it < 2; ++it) {
        int s   = tid + it * 256;           // 0..511 slots of 8 bf16
        int row = s >> 3;
        int o8  = (s & 7) * 8;
        int g   = nbase + row;
        uint4 v = *(const uint4*)&xb[(size_t)(g < N ? g : 0) * 64 + o8];
        *(uint4*)&smA[row][64 + o8] = v;
    }
    __syncthreads();   // all mean reads done -> out writes legal (aliasing)

    bf16x8 a0 = *(const bf16x8*)&smA[w * 16 + lo][ 0 + hi * 8];
    bf16x8 a1 = *(const bf16x8*)&smA[w * 16 + lo][32 + hi * 8];
    bf16x8 a2 = *(const bf16x8*)&smA[w * 16 + lo][64 + hi * 8];
    bf16x8 a3 = *(const bf16x8*)&smA[w * 16 + lo][96 + hi * 8];

    floatx4 c[4];
    #pragma unroll
    for (int ct = 0; ct < 4; ++ct) {
        float b = bias[ct * 16 + lo];
        c[ct] = (floatx4){b, b, b, b};
    }

    #pragma unroll
    for (int ct = 0; ct < 4; ++ct) {
        int j = ct * 16 + lo;
        bf16x8 b0 = *(const bf16x8*)&smB[j][ 0 + hi * 8];
        bf16x8 b1 = *(const bf16x8*)&smB[j][32 + hi * 8];
        bf16x8 b2 = *(const bf16x8*)&smB[j][64 + hi * 8];
        bf16x8 b3 = *(const bf16x8*)&smB[j][96 + hi * 8];
        c[ct] = __builtin_amdgcn_mfma_f32_16x16x32_bf16(a0, b0, c[ct], 0, 0, 0);
        c[ct] = __builtin_amdgcn_mfma_f32_16x16x32_bf16(a1, b1, c[ct], 0, 0, 0);
        c[ct] = __builtin_amdgcn_mfma_f32_16x16x32_bf16(a2, b2, c[ct], 0, 0, 0);
        c[ct] = __builtin_amdgcn_mfma_f32_16x16x32_bf16(a3, b3, c[ct], 0, 0, 0);
    }

    float s[4], q[4];
    #pragma unroll
    for (int p = 0; p < 4; ++p) {
        s[p] = c[0][p] + c[1][p] + c[2][p] + c[3][p];
        q[p] = c[0][p]*c[0][p] + c[1][p]*c[1][p]
             + c[2][p]*c[2][p] + c[3][p]*c[3][p];
        #pragma unroll
        for (int off = 1; off < 16; off <<= 1) {
            s[p] += __shfl_xor(s[p], off);
            q[p] += __shfl_xor(q[p], off);
        }
    }

    #pragma unroll
    for (int p = 0; p < 4; ++p) {
        int node = nbase + w * 16 + hi * 4 + p;   // C row = hi*4+p
        if (node >= N) continue;
        float mu  = s[p] * (1.0f / 64.0f);
        float var = q[p] * (1.0f / 64.0f) - mu * mu;
        float rr  = rsqrtf(var + LN_EPS);
        #pragma unroll
        for (int ct = 0; ct < 4; ++ct) {
            int col = ct * 16 + lo;
            float hn = (c[ct][p] - mu) * rr * gamma[col] + beta[col];
            hn = hn > 0.f ? hn : __expf(hn) - 1.0f;
            out[(size_t)node * 64 + col] = hn;
        }
    }
}

extern "C" void kernel_launch(void* const* d_in, const int* in_sizes, int n_in,
                              void* d_out, int out_size, void* d_ws, size_t ws_size,
                              hipStream_t stream) {
    const float* x     = (const float*)d_in[0];
    const int*   ei    = (const int*)  d_in[1];
    const float* Wl    = (const float*)d_in[2];
    const float* Wr    = (const float*)d_in[3];
    const float* bias  = (const float*)d_in[4];
    const float* gamma = (const float*)d_in[5];
    const float* beta  = (const float*)d_in[6];

    int N  = in_sizes[0] / 64;
    int E  = in_sizes[1] / 2;
    int NB = (N + BNODE - 1) >> BSH;       // 782 buckets

    unsigned short* xb = (unsigned short*)d_ws;        // N*64 bf16 (16B-aligned)
    int* bcount   = (int*)(xb + (size_t)N * 64);       // NB
    int* bbase    = bcount + NB;            // NB+1
    int* gcursor  = bbase + (NB + 1);       // NB
    int* rowstart = gcursor + NB;           // N+1
    int* ebuf     = rowstart + (N + 1);     // E (packed src | dstlocal<<17)
    int* esrc     = ebuf + E;               // E (CSR-ordered src)
    float* mean   = (float*)d_out;          // N*64; mfma reads rows pre-barrier

    cvt_kernel<<<(N * 64 + 2047) / 2048, 256, 0, stream>>>(x, xb, N * 64,
                                                           bcount, NB);

    int ebl = (E + EPB - 1) / EPB;
    bucket_hist_kernel<<<ebl, 256, 0, stream>>>(ei, bcount, E, NB);

    bucket_scan_kernel<<<1, 256, 0, stream>>>(bcount, bbase, gcursor, NB, E);

    bucket_scatter_kernel<<<ebl, 256, 0, stream>>>(ei, gcursor, ebuf, E, NB);

    csrsort_kernel<<<NB, 256, 0, stream>>>(bbase, ebuf, esrc, rowstart, N);

    gather_kernel<<<(N + 3) / 4, 256, 0, stream>>>(xb, rowstart, esrc, mean, N);

    mfma_mlp_kernel<<<(N + 63) / 64, 256, 0, stream>>>(xb, mean, Wl, Wr, bias,
                                                       gamma, beta,
                                                       (float*)d_out, N);
}